// Round 1
// baseline (2673.569 us; speedup 1.0000x reference)
//
#include <hip/hip_runtime.h>

// Problem dims
#define B_    2
#define CIN   128
#define COUT  128
#define DD    16
#define HH    32
#define WW    32
// x strides (floats): [b][ci][d][h][w]
#define XS_CI (DD*HH*WW)       // 16384
#define XS_B  (CIN*XS_CI)      // 2097152
// out strides: [b][co][d2][h2][w2], d2=32,h2=64,w2=64
#define OS_H2 64
#define OS_D2 (64*64)          // 4096
#define OS_CO (32*64*64)       // 131072
#define OS_B  (COUT*OS_CO)     // 16777216

// Each block: fixed (b, co, m_d, m_h-chunk of 8). 256 threads, each thread
// computes the 2x2x2 output octet for one input-space position (m_d,m_h,m_w).
// Weights are folded per-parity into E[ci][par*8+t] in LDS:
//   per dim, parity e, tap t: source kernel indices
//     e=0: t=0 -> {0}   (x[m-1]),  t=1 -> {1,2} (x[m])
//     e=1: t=0 -> {0,1} (x[m]),    t=1 -> {2}   (x[m+1])
// Output o[2m+e] uses neighborhood index (t+e) in the 3-wide x window [m-1,m,m+1].
__global__ __launch_bounds__(256) void upconv_fold_kernel(
    const float* __restrict__ x, const float* __restrict__ Wk,
    const float* __restrict__ bias, float* __restrict__ out)
{
    __shared__ float E[CIN][64];   // 32 KiB
    const int tid = threadIdx.x;
    const int co  = blockIdx.y;
    const int b   = blockIdx.z;
    const int bx  = blockIdx.x;
    const int m_d  = bx >> 2;          // 0..15
    const int m_h0 = (bx & 3) * 8;     // 0,8,16,24

    // ---- fold weights for this co into LDS ----
    const float* wco = Wk + co * (CIN * 27);
    for (int k = tid; k < CIN * 64; k += 256) {
        int ci = k >> 6;
        int r  = k & 63;
        int par = r >> 3, t = r & 7;
        int ed = (par >> 2) & 1, eh = (par >> 1) & 1, ew = par & 1;
        int td = (t >> 2) & 1,  th = (t >> 1) & 1,  tw = t & 1;
        int dlo = ed ? (td ? 2 : 0) : (td ? 1 : 0);
        int dhi = ed ? (td ? 2 : 1) : (td ? 2 : 0);
        int hlo = eh ? (th ? 2 : 0) : (th ? 1 : 0);
        int hhi = eh ? (th ? 2 : 1) : (th ? 2 : 0);
        int wlo = ew ? (tw ? 2 : 0) : (tw ? 1 : 0);
        int whi = ew ? (tw ? 2 : 1) : (tw ? 2 : 0);
        float s = 0.f;
        for (int kd = dlo; kd <= dhi; ++kd)
            for (int kh = hlo; kh <= hhi; ++kh)
                for (int kw = wlo; kw <= whi; ++kw)
                    s += wco[ci * 27 + kd * 9 + kh * 3 + kw];
        E[ci][r] = s;
    }
    __syncthreads();

    const int m_w = tid & 31;
    const int m_h = m_h0 + (tid >> 5);

    float acc[8];
    const float bv = bias[co];
    #pragma unroll
    for (int p = 0; p < 8; ++p) acc[p] = bv;

    const float* xb = x + (size_t)b * XS_B + m_d * (HH * WW) + m_h * WW + m_w;
    const bool vd[3] = { m_d > 0, true, m_d < DD - 1 };
    const bool vh[3] = { m_h > 0, true, m_h < HH - 1 };
    const bool vw[3] = { m_w > 0, true, m_w < WW - 1 };

    for (int ci = 0; ci < CIN; ++ci) {
        const float* xc = xb + ci * XS_CI;
        float xv[27];
        #pragma unroll
        for (int jd = 0; jd < 3; ++jd)
            #pragma unroll
            for (int jh = 0; jh < 3; ++jh)
                #pragma unroll
                for (int jw = 0; jw < 3; ++jw) {
                    const bool v = vd[jd] && vh[jh] && vw[jw];
                    const int off = (jd - 1) * (HH * WW) + (jh - 1) * WW + (jw - 1);
                    xv[jd * 9 + jh * 3 + jw] = v ? xc[off] : 0.f;
                }
        const float4* e4 = reinterpret_cast<const float4*>(&E[ci][0]);
        #pragma unroll
        for (int par = 0; par < 8; ++par) {
            const int ed = (par >> 2) & 1, eh = (par >> 1) & 1, ew = par & 1;
            const float4 e0 = e4[par * 2];
            const float4 e1 = e4[par * 2 + 1];
            float s = acc[par];
            s += e0.x * xv[(0 + ed) * 9 + (0 + eh) * 3 + (0 + ew)];
            s += e0.y * xv[(0 + ed) * 9 + (0 + eh) * 3 + (1 + ew)];
            s += e0.z * xv[(0 + ed) * 9 + (1 + eh) * 3 + (0 + ew)];
            s += e0.w * xv[(0 + ed) * 9 + (1 + eh) * 3 + (1 + ew)];
            s += e1.x * xv[(1 + ed) * 9 + (0 + eh) * 3 + (0 + ew)];
            s += e1.y * xv[(1 + ed) * 9 + (0 + eh) * 3 + (1 + ew)];
            s += e1.z * xv[(1 + ed) * 9 + (1 + eh) * 3 + (0 + ew)];
            s += e1.w * xv[(1 + ed) * 9 + (1 + eh) * 3 + (1 + ew)];
            acc[par] = s;
        }
    }

    float* ob = out + (size_t)b * OS_B + (size_t)co * OS_CO
              + (2 * m_d) * OS_D2 + (2 * m_h) * OS_H2 + 2 * m_w;
    #pragma unroll
    for (int par = 0; par < 8; ++par) {
        const int ed = (par >> 2) & 1, eh = (par >> 1) & 1, ew = par & 1;
        ob[ed * OS_D2 + eh * OS_H2 + ew] = acc[par];
    }
}

extern "C" void kernel_launch(void* const* d_in, const int* in_sizes, int n_in,
                              void* d_out, int out_size, void* d_ws, size_t ws_size,
                              hipStream_t stream) {
    const float* x    = (const float*)d_in[0];
    const float* Wk   = (const float*)d_in[1];
    const float* bias = (const float*)d_in[2];
    float* out        = (float*)d_out;

    dim3 grid(DD * (HH / 8), COUT, B_);   // (64, 128, 2)
    upconv_fold_kernel<<<grid, 256, 0, stream>>>(x, Wk, bias, out);
}

// Round 2
// 373.352 us; speedup vs baseline: 7.1610x; 7.1610x over previous
//
#include <hip/hip_runtime.h>
#include <hip/hip_bf16.h>

// Problem dims
#define B_    2
#define CIN   128
#define COUT  128
#define DD    16
#define HH    32
#define WW    32
// x strides (floats): [b][ci][d][h][w]
#define XS_CI (DD*HH*WW)       // 16384
#define XS_B  (CIN*XS_CI)      // 2097152
// out strides: [b][co][d2][h2][w2], d2=32,h2=64,w2=64
#define OS_H2 64
#define OS_D2 (64*64)          // 4096
#define OS_CO (32*64*64)       // 131072
#define OS_B  (COUT*OS_CO)     // 16777216

typedef __attribute__((ext_vector_type(8))) short   short8;   // 8 bf16 = 4 VGPR
typedef __attribute__((ext_vector_type(4))) float   floatx4;  // MFMA C/D

static __device__ __forceinline__ unsigned short f2bf(float f) {
    union { __hip_bfloat16 h; unsigned short u; } cv;
    cv.h = __float2bfloat16(f);
    return cv.u;
}

// ---------------------------------------------------------------------------
// Kernel 1: fold 3x3x3 weights into per-parity 2x2x2 effective kernels E_p,
// written bf16 in MFMA A-fragment order:
//   Afold[p][ks][ct][lane][j],  k = ks*32 + (lane>>4)*8 + j,  co = ct*16 + (lane&15)
//   k = ci*8 + t,  t = td*4 + th*2 + tw (tap within 2x2x2 window)
// Per-dim fold (verified in round 1):
//   e=0: t=0 -> {0},   t=1 -> {1,2}
//   e=1: t=0 -> {0,1}, t=1 -> {2}
// ---------------------------------------------------------------------------
__global__ __launch_bounds__(256) void fold_kernel(const float* __restrict__ Wk,
                                                   unsigned short* __restrict__ Afold) {
    const int t = blockIdx.x * 256 + threadIdx.x;   // 0 .. 131071
    const int p  = t >> 14;
    const int ks = (t >> 9) & 31;
    const int ct = (t >> 6) & 7;
    const int l  = t & 63;
    const int co = ct * 16 + (l & 15);
    const int ci = ks * 4 + (l >> 4);
    const int ed = (p >> 2) & 1, eh = (p >> 1) & 1, ew = p & 1;

    const float* w = Wk + (co * CIN + ci) * 27;
    float wv[27];
    #pragma unroll
    for (int i = 0; i < 27; ++i) wv[i] = w[i];

    short8 pk;
    #pragma unroll
    for (int tt = 0; tt < 8; ++tt) {
        const int td = (tt >> 2) & 1, th = (tt >> 1) & 1, tw = tt & 1;
        const int dlo = ed ? (td ? 2 : 0) : (td ? 1 : 0);
        const int dhi = ed ? (td ? 2 : 1) : (td ? 2 : 0);
        const int hlo = eh ? (th ? 2 : 0) : (th ? 1 : 0);
        const int hhi = eh ? (th ? 2 : 1) : (th ? 2 : 0);
        const int wlo = ew ? (tw ? 2 : 0) : (tw ? 1 : 0);
        const int whi = ew ? (tw ? 2 : 1) : (tw ? 2 : 0);
        float s = 0.f;
        for (int kd = dlo; kd <= dhi; ++kd)
            for (int kh = hlo; kh <= hhi; ++kh)
                for (int kw = wlo; kw <= whi; ++kw)
                    s += wv[kd * 9 + kh * 3 + kw];
        pk[tt] = (short)f2bf(s);
    }
    reinterpret_cast<short8*>(Afold)[t] = pk;
}

// ---------------------------------------------------------------------------
// Kernel 2: per-parity implicit GEMM.  Block: one parity p, one batch b, one
// d-plane, 4 h-rows x 32 w = N-tile 128, all 128 co.  K = CIN*8 = 1024 in 16
// chunks of 64 (8 ci).  4 waves, each owns a 64co x 64n quadrant.
// B-tile LDS layout: [n=128][k=64] bf16, byte = n*128 + ((klocal*2) ^ ((n&7)<<4))
// ---------------------------------------------------------------------------
__global__ __launch_bounds__(256) void upconv_mfma(const float* __restrict__ x,
                                                   const unsigned short* __restrict__ Afold,
                                                   const float* __restrict__ bias,
                                                   float* __restrict__ out) {
    __shared__ short Bt[128 * 64];   // 16 KiB
    char* Btc = reinterpret_cast<char*>(Bt);

    const int tid  = threadIdx.x;
    const int wave = tid >> 6;
    const int lane = tid & 63;

    const int d      = blockIdx.x >> 3;
    const int h_base = (blockIdx.x & 7) * 4;
    const int p      = blockIdx.y;
    const int b      = blockIdx.z;
    const int ed = (p >> 2) & 1, eh = (p >> 1) & 1, ew = p & 1;

    // ---- staging-thread geometry (invariant over k) ----
    const int n_s   = tid & 127;          // position within N-tile
    const int cils  = tid >> 7;           // ci_loc = cils + 2*i
    const int hs    = h_base + (n_s >> 5);
    const int ws_   = n_s & 31;
    const int d0 = d + ed - 1, h0 = hs + eh - 1, w0 = ws_ + ew - 1;

    int   off[8];
    bool  ok[8];
    #pragma unroll
    for (int tt = 0; tt < 8; ++tt) {
        const int td = (tt >> 2) & 1, th = (tt >> 1) & 1, tw = tt & 1;
        const int dd = d0 + td, hh = h0 + th, ww = w0 + tw;
        ok[tt]  = ((unsigned)dd < DD) && ((unsigned)hh < HH) && ((unsigned)ww < WW);
        off[tt] = dd * (HH * WW) + hh * WW + ww;
    }
    const int sw    = (n_s & 7) << 4;               // XOR swizzle bits 4..6
    const int wbase = n_s * 128;
    const float* xb = x + (size_t)b * XS_B;

    // ---- MFMA-read geometry ----
    const int co0 = (wave >> 1) * 64;
    const int n0  = (wave & 1) * 64;
    const int ct0 = (wave >> 1) * 4;                // global co-tile base

    floatx4 acc[4][4];
    #pragma unroll
    for (int i = 0; i < 4; ++i)
        #pragma unroll
        for (int j = 0; j < 4; ++j)
            acc[i][j] = (floatx4){0.f, 0.f, 0.f, 0.f};

    const short8* Ap = reinterpret_cast<const short8*>(Afold);

    for (int kc = 0; kc < 16; ++kc) {
        // A fragments for this chunk (global, L2-resident, fully coalesced)
        short8 a[2][4];
        #pragma unroll
        for (int ksl = 0; ksl < 2; ++ksl) {
            const int ks = kc * 2 + ksl;
            #pragma unroll
            for (int ct = 0; ct < 4; ++ct)
                a[ksl][ct] = Ap[((p * 32 + ks) * 8 + ct0 + ct) * 64 + lane];
        }

        __syncthreads();   // previous chunk's B reads complete

        // ---- stage B tile: gather 2x2x2 taps, convert, swizzled ds_write ----
        #pragma unroll
        for (int i = 0; i < 4; ++i) {
            const int ci_loc = cils + 2 * i;
            const float* xc = xb + (size_t)(kc * 8 + ci_loc) * XS_CI;
            short8 pk;
            #pragma unroll
            for (int tt = 0; tt < 8; ++tt) {
                const float v = ok[tt] ? xc[off[tt]] : 0.f;
                pk[tt] = (short)f2bf(v);
            }
            *reinterpret_cast<short8*>(Btc + wbase + ((ci_loc * 16) ^ sw)) = pk;
        }

        __syncthreads();

        // ---- MFMA ----
        #pragma unroll
        for (int ksl = 0; ksl < 2; ++ksl) {
            short8 bf[4];
            #pragma unroll
            for (int nt = 0; nt < 4; ++nt) {
                const int n = n0 + nt * 16 + (lane & 15);
                const int kb = ksl * 64 + (lane >> 4) * 16;
                bf[nt] = *reinterpret_cast<const short8*>(
                    Btc + n * 128 + (kb ^ ((n & 7) << 4)));
            }
            #pragma unroll
            for (int ct = 0; ct < 4; ++ct)
                #pragma unroll
                for (int nt = 0; nt < 4; ++nt)
                    acc[ct][nt] = __builtin_amdgcn_mfma_f32_16x16x32_bf16(
                        a[ksl][ct], bf[nt], acc[ct][nt], 0, 0, 0);
        }
    }

    // ---- epilogue: add bias, scatter to upsampled layout ----
    float* ob = out + (size_t)b * OS_B + (size_t)(2 * d + ed) * OS_D2;
    #pragma unroll
    for (int ct = 0; ct < 4; ++ct) {
        #pragma unroll
        for (int j = 0; j < 4; ++j) {
            const int co = co0 + ct * 16 + (lane >> 4) * 4 + j;
            const float bv = bias[co];
            #pragma unroll
            for (int nt = 0; nt < 4; ++nt) {
                const int n  = n0 + nt * 16 + (lane & 15);
                const int hl = n >> 5, wl = n & 31;
                const int h2 = 2 * (h_base + hl) + eh;
                const int w2 = 2 * wl + ew;
                ob[(size_t)co * OS_CO + h2 * OS_H2 + w2] = acc[ct][nt][j] + bv;
            }
        }
    }
}

extern "C" void kernel_launch(void* const* d_in, const int* in_sizes, int n_in,
                              void* d_out, int out_size, void* d_ws, size_t ws_size,
                              hipStream_t stream) {
    const float* x    = (const float*)d_in[0];
    const float* Wk   = (const float*)d_in[1];
    const float* bias = (const float*)d_in[2];
    float* out        = (float*)d_out;
    unsigned short* Afold = (unsigned short*)d_ws;   // 2 MiB

    fold_kernel<<<512, 256, 0, stream>>>(Wk, Afold);
    dim3 grid(DD * 8, 8, B_);   // (128 d*htile, 8 parity, 2 batch)
    upconv_mfma<<<grid, 256, 0, stream>>>(x, Afold, bias, out);
}

// Round 3
// 138.780 us; speedup vs baseline: 19.2648x; 2.6902x over previous
//
#include <hip/hip_runtime.h>
#include <hip/hip_bf16.h>

// Problem dims
#define B_    2
#define CIN   128
#define COUT  128
#define DD    16
#define HH    32
#define WW    32
// x strides (floats): [b][ci][d][h][w]
#define XS_CI (DD*HH*WW)       // 16384
#define XS_B  (CIN*XS_CI)      // 2097152
// out strides: [b][co][d2][h2][w2]
#define OS_H2 64
#define OS_D2 (64*64)
#define OS_CO (32*64*64)
#define OS_B  (COUT*OS_CO)

typedef __attribute__((ext_vector_type(8))) short   short8;
typedef __attribute__((ext_vector_type(4))) float   floatx4;

static __device__ __forceinline__ unsigned short f2bf(float f) {
    union { __hip_bfloat16 h; unsigned short u; } cv;
    cv.h = __float2bfloat16(f);
    return cv.u;
}

// ---------------------------------------------------------------------------
// Kernel 1: fold 3x3x3 weights into per-parity 2x2x2 effective kernels,
// bf16, MFMA A-fragment order (unchanged from round 2; verified).
// ---------------------------------------------------------------------------
__global__ __launch_bounds__(256) void fold_kernel(const float* __restrict__ Wk,
                                                   unsigned short* __restrict__ Afold) {
    const int t = blockIdx.x * 256 + threadIdx.x;   // 0 .. 131071
    const int p  = t >> 14;
    const int ks = (t >> 9) & 31;
    const int ct = (t >> 6) & 7;
    const int l  = t & 63;
    const int co = ct * 16 + (l & 15);
    const int ci = ks * 4 + (l >> 4);
    const int ed = (p >> 2) & 1, eh = (p >> 1) & 1, ew = p & 1;

    const float* w = Wk + (co * CIN + ci) * 27;
    float wv[27];
    #pragma unroll
    for (int i = 0; i < 27; ++i) wv[i] = w[i];

    short8 pk;
    #pragma unroll
    for (int tt = 0; tt < 8; ++tt) {
        const int td = (tt >> 2) & 1, th = (tt >> 1) & 1, tw = tt & 1;
        const int dlo = ed ? (td ? 2 : 0) : (td ? 1 : 0);
        const int dhi = ed ? (td ? 2 : 1) : (td ? 2 : 0);
        const int hlo = eh ? (th ? 2 : 0) : (th ? 1 : 0);
        const int hhi = eh ? (th ? 2 : 1) : (th ? 2 : 0);
        const int wlo = ew ? (tw ? 2 : 0) : (tw ? 1 : 0);
        const int whi = ew ? (tw ? 2 : 1) : (tw ? 2 : 0);
        float s = 0.f;
        for (int kd = dlo; kd <= dhi; ++kd)
            for (int kh = hlo; kh <= hhi; ++kh)
                for (int kw = wlo; kw <= whi; ++kw)
                    s += wv[kd * 9 + kh * 3 + kw];
        pk[tt] = (short)f2bf(s);
    }
    reinterpret_cast<short8*>(Afold)[t] = pk;
}

// ---------------------------------------------------------------------------
// Kernel 2: per-parity implicit GEMM, software-pipelined.
//   - double-buffered B tile in LDS (2 x 16 KiB), ONE barrier per K-chunk
//   - chunk kc+1's global gathers issued before chunk kc's MFMA, converted
//     next iteration (latency hidden under MFMA)
//   - barrier = lgkmcnt(0)-only + s_barrier: in-flight gathers NOT drained
// ---------------------------------------------------------------------------
__global__ __launch_bounds__(256) void upconv_mfma(const float* __restrict__ x,
                                                   const unsigned short* __restrict__ Afold,
                                                   const float* __restrict__ bias,
                                                   float* __restrict__ out) {
    __shared__ short Bt[2][128 * 64];   // 2 x 16 KiB
    char* buf0 = reinterpret_cast<char*>(&Bt[0][0]);
    char* buf1 = reinterpret_cast<char*>(&Bt[1][0]);

    const int tid  = threadIdx.x;
    const int wave = tid >> 6;
    const int lane = tid & 63;

    const int d      = blockIdx.x >> 3;
    const int h_base = (blockIdx.x & 7) * 4;
    const int p      = blockIdx.y;
    const int b      = blockIdx.z;
    const int ed = (p >> 2) & 1, eh = (p >> 1) & 1, ew = p & 1;

    // ---- staging-thread geometry (k-invariant) ----
    const int n_s  = tid & 127;
    const int cils = tid >> 7;            // ci_loc = cils + 2*i
    const int hs   = h_base + (n_s >> 5);
    const int ws_  = n_s & 31;
    const int d0 = d + ed - 1, h0 = hs + eh - 1, w0 = ws_ + ew - 1;

    int  off[8];
    bool ok[8];
    #pragma unroll
    for (int tt = 0; tt < 8; ++tt) {
        const int td = (tt >> 2) & 1, th = (tt >> 1) & 1, tw = tt & 1;
        const int dd2 = d0 + td, hh2 = h0 + th, ww2 = w0 + tw;
        ok[tt]  = ((unsigned)dd2 < DD) && ((unsigned)hh2 < HH) && ((unsigned)ww2 < WW);
        off[tt] = dd2 * (HH * WW) + hh2 * WW + ww2;
    }
    const int sw    = (n_s & 7) << 4;     // XOR swizzle bits 4..6
    const int wbase = n_s * 128;
    const float* xb = x + (size_t)b * XS_B;

    // ---- MFMA-read geometry ----
    const int co0 = (wave >> 1) * 64;
    const int n0  = (wave & 1) * 64;
    const int ct0 = (wave >> 1) * 4;

    floatx4 acc[4][4];
    #pragma unroll
    for (int i = 0; i < 4; ++i)
        #pragma unroll
        for (int j = 0; j < 4; ++j)
            acc[i][j] = (floatx4){0.f, 0.f, 0.f, 0.f};

    const short8* Ap = reinterpret_cast<const short8*>(Afold);

    float raw[4][8];   // gathered fp32 for the NEXT chunk (static indices only)

    auto gather = [&](int kc) {
        #pragma unroll
        for (int i = 0; i < 4; ++i) {
            const float* xc = xb + (size_t)(kc * 8 + cils + 2 * i) * XS_CI;
            #pragma unroll
            for (int tt = 0; tt < 8; ++tt)
                raw[i][tt] = ok[tt] ? xc[off[tt]] : 0.f;
        }
    };

    auto body = [&](int kc, char* bufc, bool last) {
        // 1) A-fragment loads FIRST: the vmcnt wait for these (before MFMA)
        //    then doesn't force draining the gathers issued below.
        short8 a[2][4];
        #pragma unroll
        for (int ksl = 0; ksl < 2; ++ksl)
            #pragma unroll
            for (int ct = 0; ct < 4; ++ct)
                a[ksl][ct] = Ap[((size_t)((p * 32 + kc * 2 + ksl) * 8 + ct0 + ct)) * 64 + lane];

        // 2) convert previously-gathered chunk kc, write to LDS (swizzled)
        #pragma unroll
        for (int i = 0; i < 4; ++i) {
            short8 pk;
            #pragma unroll
            for (int tt = 0; tt < 8; ++tt) pk[tt] = (short)f2bf(raw[i][tt]);
            *reinterpret_cast<short8*>(bufc + wbase + (((cils + 2 * i) * 16) ^ sw)) = pk;
        }

        // 3) issue chunk kc+1 gathers (stay in flight across the barrier)
        if (!last) gather(kc + 1);

        // 4) barrier with LDS-visibility only — do NOT drain vmcnt
        asm volatile("s_waitcnt lgkmcnt(0)\n\ts_barrier" ::: "memory");

        // 5) MFMA
        __builtin_amdgcn_s_setprio(1);
        #pragma unroll
        for (int ksl = 0; ksl < 2; ++ksl) {
            short8 bfr[4];
            #pragma unroll
            for (int nt = 0; nt < 4; ++nt) {
                const int n  = n0 + nt * 16 + (lane & 15);
                const int kb = ksl * 64 + (lane >> 4) * 16;
                bfr[nt] = *reinterpret_cast<const short8*>(
                    bufc + n * 128 + (kb ^ ((n & 7) << 4)));
            }
            #pragma unroll
            for (int ct = 0; ct < 4; ++ct)
                #pragma unroll
                for (int nt = 0; nt < 4; ++nt)
                    acc[ct][nt] = __builtin_amdgcn_mfma_f32_16x16x32_bf16(
                        a[ksl][ct], bfr[nt], acc[ct][nt], 0, 0, 0);
        }
        __builtin_amdgcn_s_setprio(0);
    };

    gather(0);
    for (int kc = 0; kc < 16; kc += 2) {
        body(kc,     buf0, false);
        body(kc + 1, buf1, (kc + 1) == 15);
    }

    // ---- epilogue: add bias, scatter to upsampled layout ----
    float* ob = out + (size_t)b * OS_B + (size_t)(2 * d + ed) * OS_D2;
    #pragma unroll
    for (int ct = 0; ct < 4; ++ct) {
        #pragma unroll
        for (int j = 0; j < 4; ++j) {
            const int co = co0 + ct * 16 + (lane >> 4) * 4 + j;
            const float bv = bias[co];
            #pragma unroll
            for (int nt = 0; nt < 4; ++nt) {
                const int n  = n0 + nt * 16 + (lane & 15);
                const int hl = n >> 5, wl = n & 31;
                const int h2 = 2 * (h_base + hl) + eh;
                const int w2 = 2 * wl + ew;
                ob[(size_t)co * OS_CO + h2 * OS_H2 + w2] = acc[ct][nt][j] + bv;
            }
        }
    }
}

extern "C" void kernel_launch(void* const* d_in, const int* in_sizes, int n_in,
                              void* d_out, int out_size, void* d_ws, size_t ws_size,
                              hipStream_t stream) {
    const float* x    = (const float*)d_in[0];
    const float* Wk   = (const float*)d_in[1];
    const float* bias = (const float*)d_in[2];
    float* out        = (float*)d_out;
    unsigned short* Afold = (unsigned short*)d_ws;   // 2 MiB

    fold_kernel<<<512, 256, 0, stream>>>(Wk, Afold);
    dim3 grid(DD * 8, 8, B_);   // (128, 8 parity, 2 batch)
    upconv_mfma<<<grid, 256, 0, stream>>>(x, Afold, bias, out);
}

// Round 4
// 114.006 us; speedup vs baseline: 23.4511x; 1.2173x over previous
//
#include <hip/hip_runtime.h>
#include <hip/hip_bf16.h>

// Problem dims
#define B_    2
#define CIN   128
#define COUT  128
#define DD    16
#define HH    32
#define WW    32
#define XS_CI (DD*HH*WW)       // 16384
#define XS_B  (CIN*XS_CI)
// out strides: [b][co][d2][h2][w2]
#define OS_H2 64
#define OS_D2 (64*64)
#define OS_CO (32*64*64)
#define OS_B  (COUT*OS_CO)

// padded bf16 x: [b][ci][18][34][36], interior at d:1..16, h:1..32, w:2..33
#define PD_D  18
#define PD_H  34
#define PD_W  36
#define PD_HW (PD_H*PD_W)      // 1224
#define PD_CI (PD_D*PD_HW)     // 22032
#define AFOLD_BYTES (8*32*8*64*16)          // 2 MiB
#define XPAD_ELEMS  ((size_t)B_*CIN*PD_CI)  // 5,640,192 bf16
#define XPAD_BYTES  (XPAD_ELEMS*2)

typedef __attribute__((ext_vector_type(8))) short        short8;
typedef __attribute__((ext_vector_type(4))) float        floatx4;
typedef __attribute__((ext_vector_type(4))) unsigned int uint4v;

static __device__ __forceinline__ unsigned f2bf(float f) {
    union { __hip_bfloat16 h; unsigned short u; } cv;
    cv.h = __float2bfloat16(f);
    return (unsigned)cv.u;
}

// ---------------------------------------------------------------------------
// Kernel 1: fold 3x3x3 weights into per-parity 2x2x2 effective kernels,
// bf16, MFMA A-fragment order (verified rounds 2-3).
// ---------------------------------------------------------------------------
__global__ __launch_bounds__(256) void fold_kernel(const float* __restrict__ Wk,
                                                   unsigned short* __restrict__ Afold) {
    const int t = blockIdx.x * 256 + threadIdx.x;   // 0 .. 131071
    const int p  = t >> 14;
    const int ks = (t >> 9) & 31;
    const int ct = (t >> 6) & 7;
    const int l  = t & 63;
    const int co = ct * 16 + (l & 15);
    const int ci = ks * 4 + (l >> 4);
    const int ed = (p >> 2) & 1, eh = (p >> 1) & 1, ew = p & 1;

    const float* w = Wk + (co * CIN + ci) * 27;
    float wv[27];
    #pragma unroll
    for (int i = 0; i < 27; ++i) wv[i] = w[i];

    short8 pk;
    #pragma unroll
    for (int tt = 0; tt < 8; ++tt) {
        const int td = (tt >> 2) & 1, th = (tt >> 1) & 1, tw = tt & 1;
        const int dlo = ed ? (td ? 2 : 0) : (td ? 1 : 0);
        const int dhi = ed ? (td ? 2 : 1) : (td ? 2 : 0);
        const int hlo = eh ? (th ? 2 : 0) : (th ? 1 : 0);
        const int hhi = eh ? (th ? 2 : 1) : (th ? 2 : 0);
        const int wlo = ew ? (tw ? 2 : 0) : (tw ? 1 : 0);
        const int whi = ew ? (tw ? 2 : 1) : (tw ? 2 : 0);
        float s = 0.f;
        for (int kd = dlo; kd <= dhi; ++kd)
            for (int kh = hlo; kh <= hhi; ++kh)
                for (int kw = wlo; kw <= whi; ++kw)
                    s += wv[kd * 9 + kh * 3 + kw];
        pk[tt] = (short)f2bf(s);
    }
    reinterpret_cast<short8*>(Afold)[t] = pk;
}

// ---------------------------------------------------------------------------
// Kernel 2: convert+pad x into bf16 [b][ci][18][34][36] (borders pre-zeroed
// by hipMemsetAsync). One thread per w-pair; aligned u32 stores.
// ---------------------------------------------------------------------------
__global__ __launch_bounds__(256) void pad_kernel(const float* __restrict__ x,
                                                  unsigned* __restrict__ xp32) {
    const int idx = blockIdx.x * 256 + threadIdx.x;   // 0 .. 2,097,151
    const int w2 = idx & 15;
    const int h  = (idx >> 4) & 31;
    const int d  = (idx >> 9) & 15;
    const int ci = (idx >> 13) & 127;
    const int b  = (idx >> 20) & 1;
    const float2 v = *reinterpret_cast<const float2*>(
        x + (size_t)((b * CIN + ci) * DD + d) * (HH * WW) + h * WW + w2 * 2);
    xp32[(size_t)((b * CIN + ci) * PD_D + d + 1) * (PD_HW / 2)
         + (h + 1) * (PD_W / 2) + (w2 + 1)] = f2bf(v.x) | (f2bf(v.y) << 16);
}

// ---------------------------------------------------------------------------
// Kernel 3: per-parity implicit GEMM, software-pipelined (r3 structure).
// Staging rewritten: aligned bf16 pair-gathers from padded x, no cvt, no
// predication.  Each thread stages 2 n (w-pair) x 2 ci per chunk.
// ---------------------------------------------------------------------------
__global__ __launch_bounds__(256, 3) void upconv_mfma(
    const unsigned short* __restrict__ xp,
    const unsigned short* __restrict__ Afold,
    const float* __restrict__ bias,
    float* __restrict__ out)
{
    __shared__ short Bt[2][128 * 64];   // 2 x 16 KiB
    char* buf0 = reinterpret_cast<char*>(&Bt[0][0]);
    char* buf1 = reinterpret_cast<char*>(&Bt[1][0]);

    const int tid  = threadIdx.x;
    const int wave = tid >> 6;
    const int lane = tid & 63;

    const int d      = blockIdx.x >> 3;
    const int h_base = (blockIdx.x & 7) * 4;
    const int p      = blockIdx.y;
    const int b      = blockIdx.z;
    const int ed = (p >> 2) & 1, eh = (p >> 1) & 1, ew = p & 1;

    // ---- staging geometry (chunk-invariant) ----
    const int npair = tid & 63;
    const int grp   = tid >> 6;                 // ci group 0..3
    const int hl    = npair >> 4;               // 0..3
    const int wlp   = (npair & 15) * 2;         // 0,2,..,30
    const int n_a   = hl * 32 + wlp;
    const int n_b   = n_a + 1;
    const int pd  = d + ed;
    const int ph  = h_base + hl + eh;
    const int pwb = wlp + 2 * ew;               // aligned base elem (even)
    const int roff = pd * PD_HW + ph * PD_W + pwb;          // elements
    const unsigned short* xpb = xp + (size_t)b * CIN * PD_CI;

    int waddr_a[2], waddr_b[2];
    #pragma unroll
    for (int i = 0; i < 2; ++i) {
        const int cl = grp * 2 + i;             // ci_loc within chunk
        waddr_a[i] = n_a * 128 + ((cl * 16) ^ ((n_a & 7) << 4));
        waddr_b[i] = n_b * 128 + ((cl * 16) ^ ((n_b & 7) << 4));
    }

    // ---- MFMA-read geometry (chunk-invariant) ----
    const int co0 = (wave >> 1) * 64;
    const int n0  = (wave & 1) * 64;
    const int ct0 = (wave >> 1) * 4;
    int raddr[2][4];
    #pragma unroll
    for (int ksl = 0; ksl < 2; ++ksl)
        #pragma unroll
        for (int nt = 0; nt < 4; ++nt) {
            const int n  = n0 + nt * 16 + (lane & 15);
            const int kb = ksl * 64 + (lane >> 4) * 16;
            raddr[ksl][nt] = n * 128 + (kb ^ ((n & 7) << 4));
        }

    floatx4 acc[4][4];
    #pragma unroll
    for (int i = 0; i < 4; ++i)
        #pragma unroll
        for (int j = 0; j < 4; ++j)
            acc[i][j] = (floatx4){0.f, 0.f, 0.f, 0.f};

    const short8* Ap = reinterpret_cast<const short8*>(Afold);

    unsigned g[2][4][2];   // [ci][row(td,th)][dword]
    auto gather = [&](int kc) {
        #pragma unroll
        for (int i = 0; i < 2; ++i) {
            const char* bc = reinterpret_cast<const char*>(
                xpb + (size_t)(kc * 8 + grp * 2 + i) * PD_CI + roff);
            g[i][0][0] = *(const unsigned*)(bc + 0);
            g[i][0][1] = *(const unsigned*)(bc + 4);
            g[i][1][0] = *(const unsigned*)(bc + 72);
            g[i][1][1] = *(const unsigned*)(bc + 76);
            g[i][2][0] = *(const unsigned*)(bc + 2448);
            g[i][2][1] = *(const unsigned*)(bc + 2452);
            g[i][3][0] = *(const unsigned*)(bc + 2520);
            g[i][3][1] = *(const unsigned*)(bc + 2524);
        }
    };

    auto body = [&](int kc, char* bufc, bool last) {
        // 1) A-fragment loads first (L2-resident)
        short8 a[2][4];
        #pragma unroll
        for (int ksl = 0; ksl < 2; ++ksl)
            #pragma unroll
            for (int ct = 0; ct < 4; ++ct)
                a[ksl][ct] = Ap[(size_t)((p * 32 + kc * 2 + ksl) * 8 + ct0 + ct) * 64 + lane];

        // 2) extract tap-pairs from previous gather, write LDS (swizzled)
        #pragma unroll
        for (int i = 0; i < 2; ++i) {
            unsigned pa[4], pb[4];
            #pragma unroll
            for (int r = 0; r < 4; ++r) {
                const unsigned l0 = g[i][r][0], l1 = g[i][r][1];
                const unsigned mid = (l0 >> 16) | (l1 << 16);
                pa[r] = ew ? l0  : mid;
                pb[r] = ew ? mid : l1;
            }
            *(uint4v*)(bufc + waddr_a[i]) = (uint4v){pa[0], pa[1], pa[2], pa[3]};
            *(uint4v*)(bufc + waddr_b[i]) = (uint4v){pb[0], pb[1], pb[2], pb[3]};
        }

        // 3) issue next chunk's gathers (stay in flight across barrier)
        if (!last) gather(kc + 1);

        // 4) LDS-visibility-only barrier (do NOT drain vmcnt)
        asm volatile("s_waitcnt lgkmcnt(0)\n\ts_barrier" ::: "memory");

        // 5) MFMA
        __builtin_amdgcn_s_setprio(1);
        #pragma unroll
        for (int ksl = 0; ksl < 2; ++ksl) {
            short8 bfr[4];
            #pragma unroll
            for (int nt = 0; nt < 4; ++nt)
                bfr[nt] = *reinterpret_cast<const short8*>(bufc + raddr[ksl][nt]);
            #pragma unroll
            for (int ct = 0; ct < 4; ++ct)
                #pragma unroll
                for (int nt = 0; nt < 4; ++nt)
                    acc[ct][nt] = __builtin_amdgcn_mfma_f32_16x16x32_bf16(
                        a[ksl][ct], bfr[nt], acc[ct][nt], 0, 0, 0);
        }
        __builtin_amdgcn_s_setprio(0);
    };

    gather(0);
    for (int kc = 0; kc < 16; kc += 2) {
        body(kc,     buf0, false);
        body(kc + 1, buf1, (kc + 1) == 15);
    }

    // ---- epilogue: add bias, scatter to upsampled layout ----
    float* ob = out + (size_t)b * OS_B + (size_t)(2 * d + ed) * OS_D2;
    #pragma unroll
    for (int ct = 0; ct < 4; ++ct) {
        #pragma unroll
        for (int j = 0; j < 4; ++j) {
            const int co = co0 + ct * 16 + (lane >> 4) * 4 + j;
            const float bv = bias[co];
            #pragma unroll
            for (int nt = 0; nt < 4; ++nt) {
                const int n  = n0 + nt * 16 + (lane & 15);
                const int hh = n >> 5, wl = n & 31;
                const int h2 = 2 * (h_base + hh) + eh;
                const int w2 = 2 * wl + ew;
                ob[(size_t)co * OS_CO + h2 * OS_H2 + w2] = acc[ct][nt][j] + bv;
            }
        }
    }
}

extern "C" void kernel_launch(void* const* d_in, const int* in_sizes, int n_in,
                              void* d_out, int out_size, void* d_ws, size_t ws_size,
                              hipStream_t stream) {
    const float* x    = (const float*)d_in[0];
    const float* Wk   = (const float*)d_in[1];
    const float* bias = (const float*)d_in[2];
    float* out        = (float*)d_out;

    unsigned short* Afold = (unsigned short*)d_ws;
    unsigned short* xpad  = (unsigned short*)((char*)d_ws + AFOLD_BYTES);

    hipMemsetAsync(xpad, 0, XPAD_BYTES, stream);
    pad_kernel<<<8192, 256, 0, stream>>>(x, (unsigned*)xpad);
    fold_kernel<<<512, 256, 0, stream>>>(Wk, Afold);

    dim3 grid(DD * 8, 8, B_);   // (128, 8 parity, 2 batch)
    upconv_mfma<<<grid, 256, 0, stream>>>(xpad, Afold, bias, out);
}